// Round 1
// baseline (1039.530 us; speedup 1.0000x reference)
//
#include <hip/hip_runtime.h>

#define NN 100000     // nodes
#define NE 1600000    // edges
#define NG 512        // graphs
#define C_H1 64
#define C_H2 128
#define C_OUT 2

#define MM2_BLOCKS ((NN + 127) / 128)                 // 782 (128 nodes/block)
#define NB ((NN + 255) >> 8)                          // 391 dst-buckets of 256 nodes
#define PCHUNKS 512                                   // partition chunks
#define PCHUNK_E (NE / PCHUNKS)                       // 3125 edges per chunk
#define AT2_S 36                                      // K-half A-tile row stride (16B-aligned, 36%32=4 -> bank-skewed)

// ---------------- radix partition phase 1: per-chunk bucket histograms -----------
__global__ void k_hist(const int* __restrict__ ei, int* __restrict__ hist) {
    __shared__ int lh[NB];
    int tid = threadIdx.x;
    int blk = blockIdx.x;
    for (int i = tid; i < NB; i += 256) lh[i] = 0;
    __syncthreads();
    int base = blk * PCHUNK_E;
    for (int e = base + tid; e < base + PCHUNK_E; e += 256)
        atomicAdd(&lh[ei[NE + e] >> 8], 1);
    __syncthreads();
    for (int i = tid; i < NB; i += 256) hist[i * PCHUNKS + blk] = lh[i];
}

// ---------------- phase 2a: per-bucket scan over chunks (bucket-relative) --------
__global__ void k_colscan0(const int* __restrict__ hist, int* __restrict__ offs,
                           int* __restrict__ btot) {
    __shared__ int sh[256];
    int b = blockIdx.x;
    int tid = threadIdx.x;
    int v0 = hist[b * PCHUNKS + 2 * tid];
    int v1 = hist[b * PCHUNKS + 2 * tid + 1];
    sh[tid] = v0 + v1;
    __syncthreads();
    for (int off = 1; off < 256; off <<= 1) {
        int v = (tid >= off) ? sh[tid - off] : 0;
        __syncthreads();
        sh[tid] += v;
        __syncthreads();
    }
    int base = (tid == 0) ? 0 : sh[tid - 1];
    offs[b * PCHUNKS + 2 * tid]     = base;
    offs[b * PCHUNKS + 2 * tid + 1] = base + v0;
    if (tid == 255) btot[b] = sh[255];
}

// ---------------- phase 2b: exclusive scan of 391 bucket totals ------------------
__global__ void k_bbase(const int* __restrict__ btot, int* __restrict__ bbase,
                        int* __restrict__ row_ptr) {
    __shared__ int sh[256];
    int tid = threadIdx.x;
    int v0 = (2 * tid     < NB) ? btot[2 * tid]     : 0;
    int v1 = (2 * tid + 1 < NB) ? btot[2 * tid + 1] : 0;
    sh[tid] = v0 + v1;
    __syncthreads();
    for (int off = 1; off < 256; off <<= 1) {
        int v = (tid >= off) ? sh[tid - off] : 0;
        __syncthreads();
        sh[tid] += v;
        __syncthreads();
    }
    int base = (tid == 0) ? 0 : sh[tid - 1];
    if (2 * tid     < NB) bbase[2 * tid]     = base;
    if (2 * tid + 1 < NB) bbase[2 * tid + 1] = base + v0;
    if (tid == 255) { bbase[NB] = sh[255]; row_ptr[NN] = sh[255]; }   // == NE
}

// ---------------- phase 3: scatter via LDS cursors (no global atomics) -----------
__global__ void k_scatterA(const int* __restrict__ ei, const int* __restrict__ offs,
                           const int* __restrict__ bbase, int2* __restrict__ ed2) {
    __shared__ int lcur[NB];
    int tid = threadIdx.x;
    int blk = blockIdx.x;
    for (int i = tid; i < NB; i += 256) lcur[i] = bbase[i] + offs[i * PCHUNKS + blk];
    __syncthreads();
    int base = blk * PCHUNK_E;
    for (int e = base + tid; e < base + PCHUNK_E; e += 256) {
        int s = ei[e], d = ei[NE + e];
        int pos = atomicAdd(&lcur[d >> 8], 1);     // LDS atomic, low contention
        int2 v; v.x = s; v.y = d;
        ed2[pos] = v;
    }
}

// ---------------- B1: bucket-local degree -> dinv + row_ptr (no global atomics) --
__global__ void k_B1(const int2* __restrict__ ed2, const int* __restrict__ bbase,
                     float* __restrict__ dinv, int* __restrict__ row_ptr) {
    __shared__ int ldeg[256];
    __shared__ int sh[256];
    int b = blockIdx.x;
    int tid = threadIdx.x;
    int lo = b << 8;
    ldeg[tid] = 0;
    __syncthreads();
    int beg = bbase[b], end = bbase[b + 1];
    for (int j = beg + tid; j < end; j += 256)
        atomicAdd(&ldeg[ed2[j].y - lo], 1);
    __syncthreads();
    int d = ldeg[tid];
    int node = lo + tid;
    if (node < NN) dinv[node] = rsqrtf((float)d + 1.0f);
    sh[tid] = d;
    __syncthreads();
    for (int off = 1; off < 256; off <<= 1) {
        int v = (tid >= off) ? sh[tid - off] : 0;
        __syncthreads();
        sh[tid] += v;
        __syncthreads();
    }
    int excl = beg + ((tid == 0) ? 0 : sh[tid - 1]);
    if (node < NN) row_ptr[node] = excl;
}

// ---------------- repack x to float4 rows (16B gathers downstream) ---------------
__global__ void k_x4(const float* __restrict__ x, float4* __restrict__ x4) {
    int n = blockIdx.x * blockDim.x + threadIdx.x;
    if (n >= NN) return;
    float4 v; v.x = x[n * 3]; v.y = x[n * 3 + 1]; v.z = x[n * 3 + 2]; v.w = 0.f;
    x4[n] = v;
}

// ---------------- scatter pass B + fused layer-1 aggregation ---------------------
// ed is now just the src index (4B): nrm is recomputed in k_edge1 from
// aggx4[src].w (= dinv[src], packed here) * dinv[dst] -- identical fp multiply,
// so agg1 stays bitwise identical while ed traffic halves.
__global__ void k_scatterB(const int* __restrict__ row_ptr, const int2* __restrict__ ed2,
                           const float* __restrict__ dinv, const float4* __restrict__ x4,
                           int* __restrict__ ed, float4* __restrict__ aggx4) {
    __shared__ int   lcur[256];
    __shared__ float ldin[256];
    __shared__ float lax[256 * 3];
    int b = blockIdx.x;
    int lo = b << 8;
    int tid = threadIdx.x;
    int node = lo + tid;
    if (node <= NN) lcur[tid] = row_ptr[node < NN ? node : NN];
    else            lcur[tid] = 0;
    ldin[tid] = (node < NN) ? dinv[node] : 0.f;
    lax[tid] = 0.f; lax[256 + tid] = 0.f; lax[512 + tid] = 0.f;
    __syncthreads();
    int seg_beg = row_ptr[lo];
    int hi = lo + 256; if (hi > NN) hi = NN;
    int seg_end = row_ptr[hi];
    for (int j = seg_beg + tid; j < seg_end; j += 256) {
        int2 sd = ed2[j];
        int local = sd.y - lo;
        int pos = atomicAdd(&lcur[local], 1);
        float nrm = dinv[sd.x] * ldin[local];
        ed[pos] = sd.x;                                // 4B scatter (was 8B)
        float4 xs = x4[sd.x];                          // 16B gather, L2-hot (1.6MB)
        atomicAdd(&lax[local],       nrm * xs.x);      // ds_add_f32
        atomicAdd(&lax[256 + local], nrm * xs.y);
        atomicAdd(&lax[512 + local], nrm * xs.z);
    }
    __syncthreads();
    if (node < NN) {
        float di = ldin[tid];
        float s2 = di * di;
        float4 xs = x4[node];
        float4 a;
        a.x = lax[tid]       + s2 * xs.x;
        a.y = lax[256 + tid] + s2 * xs.y;
        a.z = lax[512 + tid] + s2 * xs.z;
        a.w = di;                                      // pack dinv for k_edge1
        aggx4[node] = a;
    }
}

// ---------------- layer 2 aggregate via on-the-fly h1 recompute ------------------
__global__ void k_edge1(const int* __restrict__ row_ptr, const int* __restrict__ ed,
                        const float4* __restrict__ aggx4,
                        const float* __restrict__ W1, const float* __restrict__ b1,
                        float* __restrict__ agg1) {
    __shared__ float4 lp[256];                        // 64 per wave
    int t = blockIdx.x * 256 + threadIdx.x;           // grid exact: NN*64/256
    int n = t >> 6, c = t & 63;
    int lane = threadIdx.x & 63;
    int wbase = threadIdx.x & 192;                    // wave's LDS base (0,64,128,192)

    float w0 = W1[c], w1 = W1[64 + c], w2 = W1[128 + c], bb = b1[c];
    float4 an = aggx4[n];                             // wave-uniform
    float di = an.w;                                  // dinv[n], packed by scatterB
    float hself = fmaxf(fmaf(an.x, w0, fmaf(an.y, w1, fmaf(an.z, w2, bb))), 0.f);
    float acc = di * di * hself;

    int beg = row_ptr[n], end = row_ptr[n + 1];
    for (int base = beg; base < end; base += 64) {
        int m = end - base; if (m > 64) m = 64;
        if (lane < m) {
            int s = ed[base + lane];                  // coalesced 4B (was 8B)
            float4 ax = aggx4[s];                     // random 16B, L2-hot
            float4 p; p.x = ax.x; p.y = ax.y; p.z = ax.z; p.w = ax.w * di;  // nrm
            lp[wbase + lane] = p;
        }
        int e = 0;
        for (; e + 3 < m; e += 4) {
            float4 p0 = lp[wbase + e];
            float4 p1 = lp[wbase + e + 1];
            float4 p2 = lp[wbase + e + 2];
            float4 p3 = lp[wbase + e + 3];
            float h0  = fmaxf(fmaf(p0.x, w0, fmaf(p0.y, w1, fmaf(p0.z, w2, bb))), 0.f);
            float h1v = fmaxf(fmaf(p1.x, w0, fmaf(p1.y, w1, fmaf(p1.z, w2, bb))), 0.f);
            float h2v = fmaxf(fmaf(p2.x, w0, fmaf(p2.y, w1, fmaf(p2.z, w2, bb))), 0.f);
            float h3v = fmaxf(fmaf(p3.x, w0, fmaf(p3.y, w1, fmaf(p3.z, w2, bb))), 0.f);
            acc = fmaf(p0.w, h0, acc);
            acc = fmaf(p1.w, h1v, acc);
            acc = fmaf(p2.w, h2v, acc);
            acc = fmaf(p3.w, h3v, acc);
        }
        for (; e < m; ++e) {
            float4 p = lp[wbase + e];
            float h = fmaxf(fmaf(p.x, w0, fmaf(p.y, w1, fmaf(p.z, w2, bb))), 0.f);
            acc = fmaf(p.w, h, acc);
        }
    }
    agg1[t] = acc;   // NO bias/relu here: h2 = relu(agg1 @ W2 + b2)
}

// ---------------- fused register-tiled GEMM + pool (v4: occupancy) ----------------
// Block = 128 nodes x 64 ch (channel-split, grid x2), 256 threads.
// LDS: 16 KB W2-half + 18 KB K-half A-tile + 1 KB pool = 35 KB -> 4 blocks/CU
// (was 68 KB -> 2 blocks/CU, Occupancy 13.5%, VALUBusy 32%).
// Micro-tile 8 nodes (stride-16 rows: my-groups land on disjoint bank quads,
// no 4-way at[] conflict) x 4 ch. __launch_bounds__(256,4) caps VGPR<=128.
__global__ __launch_bounds__(256, 4)
void k_mm2pool(const float* __restrict__ agg1, const float* __restrict__ W2,
               const float* __restrict__ b2, const int* __restrict__ batch,
               float* __restrict__ pooled) {
    __shared__ float wt[C_H1 * 64];       // 16 KiB: this block's 64-ch half of W2
    __shared__ float at[128 * AT2_S];     // 18 KiB: 32-k half of A-tile
    __shared__ float lpool[4 * 64];       // 1 KiB
    int tid = threadIdx.x;
    int bx  = blockIdx.x >> 1;            // node tile
    int chb = (blockIdx.x & 1) << 6;      // channel half: 0 or 64

    {
        const float4* w4 = (const float4*)W2;
        for (int i = tid; i < C_H1 * 16; i += 256) {          // 64 k x 16 float4
            int k = i >> 4, c4 = i & 15;
            *(float4*)&wt[k * 64 + c4 * 4] = w4[k * 32 + (chb >> 2) + c4];
        }
        for (int i = tid; i < 4 * 64; i += 256) lpool[i] = 0.f;
    }

    int tx = tid & 15;            // channel group: 4 ch
    int my = tid >> 4;            // node lane: rows my, my+16, ..., my+112
    int c0 = tx * 4;

    float acc[8][4];
#pragma unroll
    for (int i = 0; i < 8; ++i)
#pragma unroll
        for (int j = 0; j < 4; ++j) acc[i][j] = 0.f;

    const float4* a4 = (const float4*)(agg1 + (size_t)bx * 128 * C_H1);

#pragma unroll
    for (int h = 0; h < 2; ++h) {
        __syncthreads();                                  // covers wt stage / prev half readers
        for (int i = tid; i < 128 * 8; i += 256) {        // stage 32-k half
            int row = i >> 3, q = i & 7;
            *(float4*)&at[row * AT2_S + q * 4] = a4[row * 16 + h * 8 + q];
        }
        __syncthreads();
        int kb = h * 32;
        for (int k0 = 0; k0 < 32; k0 += 4) {
            float4 wf0 = *(const float4*)&wt[(kb + k0)     * 64 + c0];
            float4 wf1 = *(const float4*)&wt[(kb + k0 + 1) * 64 + c0];
            float4 wf2 = *(const float4*)&wt[(kb + k0 + 2) * 64 + c0];
            float4 wf3 = *(const float4*)&wt[(kb + k0 + 3) * 64 + c0];
#pragma unroll
            for (int i = 0; i < 8; ++i) {
                float4 af = *(const float4*)&at[(my + i * 16) * AT2_S + k0];
                acc[i][0] = fmaf(af.x, wf0.x, acc[i][0]);   // ascending k: bitwise
                acc[i][0] = fmaf(af.y, wf1.x, acc[i][0]);   // same chain as v3
                acc[i][0] = fmaf(af.z, wf2.x, acc[i][0]);
                acc[i][0] = fmaf(af.w, wf3.x, acc[i][0]);
                acc[i][1] = fmaf(af.x, wf0.y, acc[i][1]);
                acc[i][1] = fmaf(af.y, wf1.y, acc[i][1]);
                acc[i][1] = fmaf(af.z, wf2.y, acc[i][1]);
                acc[i][1] = fmaf(af.w, wf3.y, acc[i][1]);
                acc[i][2] = fmaf(af.x, wf0.z, acc[i][2]);
                acc[i][2] = fmaf(af.y, wf1.z, acc[i][2]);
                acc[i][2] = fmaf(af.z, wf2.z, acc[i][2]);
                acc[i][2] = fmaf(af.w, wf3.z, acc[i][2]);
                acc[i][3] = fmaf(af.x, wf0.w, acc[i][3]);
                acc[i][3] = fmaf(af.y, wf1.w, acc[i][3]);
                acc[i][3] = fmaf(af.z, wf2.w, acc[i][3]);
                acc[i][3] = fmaf(af.w, wf3.w, acc[i][3]);
            }
        }
    }

    // epilogue: bias+relu, run-length over the thread's 8 stride-16 nodes
    // (batch sorted -> gidx still monotone), LDS graph slots, few global atomics
    int nbase = bx * 128;
    int gbase = batch[nbase];                          // block-uniform
    int gidx[8];
#pragma unroll
    for (int i = 0; i < 8; ++i) {
        int node = nbase + my + i * 16;
        gidx[i] = (node < NN) ? batch[node] : -1;
    }
    float bias[4];
#pragma unroll
    for (int j = 0; j < 4; ++j) bias[j] = b2[chb + c0 + j];

#pragma unroll
    for (int j = 0; j < 4; ++j) {
        int run_g = -1;
        float rs = 0.f;
#pragma unroll
        for (int i = 0; i < 8; ++i) {
            if (gidx[i] < 0) break;
            float hcur = fmaxf(acc[i][j] + bias[j], 0.f);
            if (gidx[i] != run_g) {
                if (run_g >= 0) {
                    int slot = run_g - gbase;
                    if (slot < 4) atomicAdd(&lpool[slot * 64 + c0 + j], rs);
                    else          atomicAdd(&pooled[(run_g << 7) + chb + c0 + j], rs);
                }
                run_g = gidx[i]; rs = hcur;
            } else {
                rs += hcur;
            }
        }
        if (run_g >= 0) {
            int slot = run_g - gbase;
            if (slot < 4) atomicAdd(&lpool[slot * 64 + c0 + j], rs);
            else          atomicAdd(&pooled[(run_g << 7) + chb + c0 + j], rs);
        }
    }
    __syncthreads();
    for (int i = tid; i < 4 * 64; i += 256) {
        int slot = i >> 6, c = i & 63;
        int g = gbase + slot;
        float v = lpool[i];
        if (g < NG && v != 0.f) atomicAdd(&pooled[(g << 7) + chb + c], v);
    }
}

// ---------------- FC: out = (pooled/cnt) @ Wfc + bfc ----------------
__device__ __forceinline__ int lower_bound(const int* __restrict__ a, int n, int key) {
    int lo = 0, hi = n;
    while (lo < hi) { int mid = (lo + hi) >> 1; if (a[mid] < key) lo = mid + 1; else hi = mid; }
    return lo;
}

__global__ void k_fc(const float* __restrict__ pooled, const int* __restrict__ batch,
                     const float* __restrict__ Wfc, const float* __restrict__ bfc,
                     float* __restrict__ out) {
    int t = blockIdx.x * blockDim.x + threadIdx.x;
    if (t >= NG * C_OUT) return;
    int g = t >> 1, o = t & 1;
    int start = lower_bound(batch, NN, g);
    int end   = lower_bound(batch, NN, g + 1);
    float inv = 1.f / fmaxf((float)(end - start), 1.f);
    float s = bfc[o];
    for (int cc = 0; cc < C_H2; ++cc)
        s = fmaf(pooled[(g << 7) + cc] * inv, Wfc[cc * C_OUT + o], s);
    out[t] = s;
}

extern "C" void kernel_launch(void* const* d_in, const int* in_sizes, int n_in,
                              void* d_out, int out_size, void* d_ws, size_t ws_size,
                              hipStream_t stream) {
    const float* x     = (const float*)d_in[0];
    const int*   ei    = (const int*)d_in[1];   // [2, E]: row0 = src, row1 = dst
    const int*   batch = (const int*)d_in[2];
    const float* W1    = (const float*)d_in[3];
    const float* b1    = (const float*)d_in[4];
    const float* W2    = (const float*)d_in[5];
    const float* b2    = (const float*)d_in[6];
    const float* Wfc   = (const float*)d_in[7];
    const float* bfc   = (const float*)d_in[8];
    float* out = (float*)d_out;

    // workspace carve-out (~52 MB)
    char* p = (char*)d_ws;
    auto alloc = [&](size_t bytes) { char* r = p; p += (bytes + 255) & ~size_t(255); return r; };
    float*  dinv    = (float*) alloc((size_t)NN * 4);
    int*    row_ptr = (int*)   alloc((size_t)(NN + 1) * 4);
    int*    btot    = (int*)   alloc((size_t)NB * 4);
    int*    bbase   = (int*)   alloc((size_t)(NB + 1) * 4);
    int*    hist    = (int*)   alloc((size_t)NB * PCHUNKS * 4);
    int*    offs    = (int*)   alloc((size_t)NB * PCHUNKS * 4);
    int2*   ed2     = (int2*)  alloc((size_t)NE * 8);
    int*    ed      = (int*)   alloc((size_t)NE * 4);
    float4* x4      = (float4*)alloc((size_t)NN * 16);
    float4* aggx4   = (float4*)alloc((size_t)NN * 16);
    float*  agg1    = (float*) alloc((size_t)(NN + 128) * C_H1 * 4);  // padded
    float*  pooled  = (float*) alloc((size_t)NG * C_H2 * 4);

    hipMemsetAsync(pooled, 0, (size_t)NG * C_H2 * 4, stream);
    k_hist    <<<PCHUNKS, 256, 0, stream>>>(ei, hist);
    k_colscan0<<<NB, 256, 0, stream>>>(hist, offs, btot);
    k_bbase   <<<1, 256, 0, stream>>>(btot, bbase, row_ptr);
    k_scatterA<<<PCHUNKS, 256, 0, stream>>>(ei, offs, bbase, ed2);
    k_B1      <<<NB, 256, 0, stream>>>(ed2, bbase, dinv, row_ptr);
    k_x4      <<<(NN + 255) / 256, 256, 0, stream>>>(x, x4);
    k_scatterB<<<NB, 256, 0, stream>>>(row_ptr, ed2, dinv, x4, ed, aggx4);
    k_edge1   <<<(NN * C_H1) / 256, 256, 0, stream>>>(row_ptr, ed, aggx4, W1, b1, agg1);
    k_mm2pool <<<MM2_BLOCKS * 2, 256, 0, stream>>>(agg1, W2, b2, batch, pooled);
    k_fc      <<<(NG * C_OUT + 255) / 256, 256, 0, stream>>>(pooled, batch, Wfc, bfc, out);
}

// Round 2
// 234.275 us; speedup vs baseline: 4.4372x; 4.4372x over previous
//
#include <hip/hip_runtime.h>

#define NN 100000     // nodes
#define NE 1600000    // edges
#define NG 512        // graphs
#define C_H1 64
#define C_H2 128
#define C_OUT 2

#define MM2_BLOCKS ((NN + 127) / 128)                 // 782 (128 nodes/block)
#define NB ((NN + 255) >> 8)                          // 391 dst-buckets of 256 nodes
#define PCHUNKS 512                                   // partition chunks
#define PCHUNK_E (NE / PCHUNKS)                       // 3125 edges per chunk
#define AT2_S 36                                      // K-half A-tile row stride (16B-aligned)

// ---------------- radix partition phase 1: per-chunk bucket histograms -----------
__global__ void k_hist(const int* __restrict__ ei, int* __restrict__ hist) {
    __shared__ int lh[NB];
    int tid = threadIdx.x;
    int blk = blockIdx.x;
    for (int i = tid; i < NB; i += 256) lh[i] = 0;
    __syncthreads();
    int base = blk * PCHUNK_E;
    for (int e = base + tid; e < base + PCHUNK_E; e += 256)
        atomicAdd(&lh[ei[NE + e] >> 8], 1);
    __syncthreads();
    for (int i = tid; i < NB; i += 256) hist[i * PCHUNKS + blk] = lh[i];
}

// ---------------- phase 2a: per-bucket scan over chunks (bucket-relative) --------
__global__ void k_colscan0(const int* __restrict__ hist, int* __restrict__ offs,
                           int* __restrict__ btot) {
    __shared__ int sh[256];
    int b = blockIdx.x;
    int tid = threadIdx.x;
    int v0 = hist[b * PCHUNKS + 2 * tid];
    int v1 = hist[b * PCHUNKS + 2 * tid + 1];
    sh[tid] = v0 + v1;
    __syncthreads();
    for (int off = 1; off < 256; off <<= 1) {
        int v = (tid >= off) ? sh[tid - off] : 0;
        __syncthreads();
        sh[tid] += v;
        __syncthreads();
    }
    int base = (tid == 0) ? 0 : sh[tid - 1];
    offs[b * PCHUNKS + 2 * tid]     = base;
    offs[b * PCHUNKS + 2 * tid + 1] = base + v0;
    if (tid == 255) btot[b] = sh[255];
}

// ---------------- phase 2b: exclusive scan of 391 bucket totals ------------------
__global__ void k_bbase(const int* __restrict__ btot, int* __restrict__ bbase,
                        int* __restrict__ row_ptr) {
    __shared__ int sh[256];
    int tid = threadIdx.x;
    int v0 = (2 * tid     < NB) ? btot[2 * tid]     : 0;
    int v1 = (2 * tid + 1 < NB) ? btot[2 * tid + 1] : 0;
    sh[tid] = v0 + v1;
    __syncthreads();
    for (int off = 1; off < 256; off <<= 1) {
        int v = (tid >= off) ? sh[tid - off] : 0;
        __syncthreads();
        sh[tid] += v;
        __syncthreads();
    }
    int base = (tid == 0) ? 0 : sh[tid - 1];
    if (2 * tid     < NB) bbase[2 * tid]     = base;
    if (2 * tid + 1 < NB) bbase[2 * tid + 1] = base + v0;
    if (tid == 255) { bbase[NB] = sh[255]; row_ptr[NN] = sh[255]; }   // == NE
}

// ---------------- phase 3: scatter via LDS cursors (no global atomics) -----------
__global__ void k_scatterA(const int* __restrict__ ei, const int* __restrict__ offs,
                           const int* __restrict__ bbase, int2* __restrict__ ed2) {
    __shared__ int lcur[NB];
    int tid = threadIdx.x;
    int blk = blockIdx.x;
    for (int i = tid; i < NB; i += 256) lcur[i] = bbase[i] + offs[i * PCHUNKS + blk];
    __syncthreads();
    int base = blk * PCHUNK_E;
    for (int e = base + tid; e < base + PCHUNK_E; e += 256) {
        int s = ei[e], d = ei[NE + e];
        int pos = atomicAdd(&lcur[d >> 8], 1);     // LDS atomic, low contention
        int2 v; v.x = s; v.y = d;
        ed2[pos] = v;
    }
}

// ---------------- B1: bucket-local degree -> dinv + row_ptr (no global atomics) --
__global__ void k_B1(const int2* __restrict__ ed2, const int* __restrict__ bbase,
                     float* __restrict__ dinv, int* __restrict__ row_ptr) {
    __shared__ int ldeg[256];
    __shared__ int sh[256];
    int b = blockIdx.x;
    int tid = threadIdx.x;
    int lo = b << 8;
    ldeg[tid] = 0;
    __syncthreads();
    int beg = bbase[b], end = bbase[b + 1];
    for (int j = beg + tid; j < end; j += 256)
        atomicAdd(&ldeg[ed2[j].y - lo], 1);
    __syncthreads();
    int d = ldeg[tid];
    int node = lo + tid;
    if (node < NN) dinv[node] = rsqrtf((float)d + 1.0f);
    sh[tid] = d;
    __syncthreads();
    for (int off = 1; off < 256; off <<= 1) {
        int v = (tid >= off) ? sh[tid - off] : 0;
        __syncthreads();
        sh[tid] += v;
        __syncthreads();
    }
    int excl = beg + ((tid == 0) ? 0 : sh[tid - 1]);
    if (node < NN) row_ptr[node] = excl;
}

// ---------------- repack x to float4 rows (16B gathers downstream) ---------------
__global__ void k_x4(const float* __restrict__ x, float4* __restrict__ x4) {
    int n = blockIdx.x * blockDim.x + threadIdx.x;
    if (n >= NN) return;
    float4 v; v.x = x[n * 3]; v.y = x[n * 3 + 1]; v.z = x[n * 3 + 2]; v.w = 0.f;
    x4[n] = v;
}

// ---------------- scatter pass B + fused layer-1 aggregation ---------------------
// ed is just the src index (4B): nrm is recomputed in k_edge1 from
// aggx4[src].w (= dinv[src], packed here) * dinv[dst] -- identical fp multiply,
// so agg1 stays bitwise identical while ed traffic halves.
__global__ void k_scatterB(const int* __restrict__ row_ptr, const int2* __restrict__ ed2,
                           const float* __restrict__ dinv, const float4* __restrict__ x4,
                           int* __restrict__ ed, float4* __restrict__ aggx4) {
    __shared__ int   lcur[256];
    __shared__ float ldin[256];
    __shared__ float lax[256 * 3];
    int b = blockIdx.x;
    int lo = b << 8;
    int tid = threadIdx.x;
    int node = lo + tid;
    if (node <= NN) lcur[tid] = row_ptr[node < NN ? node : NN];
    else            lcur[tid] = 0;
    ldin[tid] = (node < NN) ? dinv[node] : 0.f;
    lax[tid] = 0.f; lax[256 + tid] = 0.f; lax[512 + tid] = 0.f;
    __syncthreads();
    int seg_beg = row_ptr[lo];
    int hi = lo + 256; if (hi > NN) hi = NN;
    int seg_end = row_ptr[hi];
    for (int j = seg_beg + tid; j < seg_end; j += 256) {
        int2 sd = ed2[j];
        int local = sd.y - lo;
        int pos = atomicAdd(&lcur[local], 1);
        float nrm = dinv[sd.x] * ldin[local];
        ed[pos] = sd.x;                                // 4B scatter (was 8B)
        float4 xs = x4[sd.x];                          // 16B gather, L2-hot (1.6MB)
        atomicAdd(&lax[local],       nrm * xs.x);      // ds_add_f32
        atomicAdd(&lax[256 + local], nrm * xs.y);
        atomicAdd(&lax[512 + local], nrm * xs.z);
    }
    __syncthreads();
    if (node < NN) {
        float di = ldin[tid];
        float s2 = di * di;
        float4 xs = x4[node];
        float4 a;
        a.x = lax[tid]       + s2 * xs.x;
        a.y = lax[256 + tid] + s2 * xs.y;
        a.z = lax[512 + tid] + s2 * xs.z;
        a.w = di;                                      // pack dinv for k_edge1
        aggx4[node] = a;
    }
}

// ---------------- layer 2 aggregate via on-the-fly h1 recompute ------------------
__global__ void k_edge1(const int* __restrict__ row_ptr, const int* __restrict__ ed,
                        const float4* __restrict__ aggx4,
                        const float* __restrict__ W1, const float* __restrict__ b1,
                        float* __restrict__ agg1) {
    __shared__ float4 lp[256];                        // 64 per wave
    int t = blockIdx.x * 256 + threadIdx.x;           // grid exact: NN*64/256
    int n = t >> 6, c = t & 63;
    int lane = threadIdx.x & 63;
    int wbase = threadIdx.x & 192;                    // wave's LDS base (0,64,128,192)

    float w0 = W1[c], w1 = W1[64 + c], w2 = W1[128 + c], bb = b1[c];
    float4 an = aggx4[n];                             // wave-uniform
    float di = an.w;                                  // dinv[n], packed by scatterB
    float hself = fmaxf(fmaf(an.x, w0, fmaf(an.y, w1, fmaf(an.z, w2, bb))), 0.f);
    float acc = di * di * hself;

    int beg = row_ptr[n], end = row_ptr[n + 1];
    for (int base = beg; base < end; base += 64) {
        int m = end - base; if (m > 64) m = 64;
        if (lane < m) {
            int s = ed[base + lane];                  // coalesced 4B (was 8B)
            float4 ax = aggx4[s];                     // random 16B, L2-hot
            float4 p; p.x = ax.x; p.y = ax.y; p.z = ax.z; p.w = ax.w * di;  // nrm
            lp[wbase + lane] = p;
        }
        int e = 0;
        for (; e + 3 < m; e += 4) {
            float4 p0 = lp[wbase + e];
            float4 p1 = lp[wbase + e + 1];
            float4 p2 = lp[wbase + e + 2];
            float4 p3 = lp[wbase + e + 3];
            float h0  = fmaxf(fmaf(p0.x, w0, fmaf(p0.y, w1, fmaf(p0.z, w2, bb))), 0.f);
            float h1v = fmaxf(fmaf(p1.x, w0, fmaf(p1.y, w1, fmaf(p1.z, w2, bb))), 0.f);
            float h2v = fmaxf(fmaf(p2.x, w0, fmaf(p2.y, w1, fmaf(p2.z, w2, bb))), 0.f);
            float h3v = fmaxf(fmaf(p3.x, w0, fmaf(p3.y, w1, fmaf(p3.z, w2, bb))), 0.f);
            acc = fmaf(p0.w, h0, acc);
            acc = fmaf(p1.w, h1v, acc);
            acc = fmaf(p2.w, h2v, acc);
            acc = fmaf(p3.w, h3v, acc);
        }
        for (; e < m; ++e) {
            float4 p = lp[wbase + e];
            float h = fmaxf(fmaf(p.x, w0, fmaf(p.y, w1, fmaf(p.z, w2, bb))), 0.f);
            acc = fmaf(p.w, h, acc);
        }
    }
    agg1[t] = acc;   // NO bias/relu here: h2 = relu(agg1 @ W2 + b2)
}

// ---------------- fused register-tiled GEMM + pool (v5: spill fix) ----------------
// Block = 128 nodes x 64 ch (channel-split, grid x2), 256 threads.
// LDS: 16 KB W2-half + 18 KB K-half A-tile + 1 KB pool = 35 KB -> 4 blocks/CU.
// v4 POST-MORTEM: __launch_bounds__(256,4) capped VGPR at 128; with the fully
// unrolled h-loop the allocator spilled acc[] to scratch -> 2.0 GB FETCH +
// 0.5 GB WRITE of spill traffic, 887 us @ 2.9 TB/s, VALUBusy 2.9%.
// Fix: cap only block size (VGPR cap 256; real demand ~80) and force
// #pragma unroll 1 on the half-loop so both halves' staging never coexists.
// Occupancy comes from the 35 KB LDS alone (4 blocks/CU).
__global__ __launch_bounds__(256)
void k_mm2pool(const float* __restrict__ agg1, const float* __restrict__ W2,
               const float* __restrict__ b2, const int* __restrict__ batch,
               float* __restrict__ pooled) {
    __shared__ float wt[C_H1 * 64];       // 16 KiB: this block's 64-ch half of W2
    __shared__ float at[128 * AT2_S];     // 18 KiB: 32-k half of A-tile
    __shared__ float lpool[4 * 64];       // 1 KiB
    int tid = threadIdx.x;
    int bx  = blockIdx.x >> 1;            // node tile
    int chb = (blockIdx.x & 1) << 6;      // channel half: 0 or 64

    {
        const float4* w4 = (const float4*)W2;
        for (int i = tid; i < C_H1 * 16; i += 256) {          // 64 k x 16 float4
            int k = i >> 4, c4 = i & 15;
            *(float4*)&wt[k * 64 + c4 * 4] = w4[k * 32 + (chb >> 2) + c4];
        }
        for (int i = tid; i < 4 * 64; i += 256) lpool[i] = 0.f;
    }

    int tx = tid & 15;            // channel group: 4 ch
    int my = tid >> 4;            // node lane: rows my, my+16, ..., my+112
    int c0 = tx * 4;

    float acc[8][4];
#pragma unroll
    for (int i = 0; i < 8; ++i)
#pragma unroll
        for (int j = 0; j < 4; ++j) acc[i][j] = 0.f;

    const float4* a4 = (const float4*)(agg1 + (size_t)bx * 128 * C_H1);

#pragma unroll 1
    for (int h = 0; h < 2; ++h) {
        __syncthreads();                                  // prev-half readers done
        for (int i = tid; i < 128 * 8; i += 256) {        // stage 32-k half
            int row = i >> 3, q = i & 7;
            *(float4*)&at[row * AT2_S + q * 4] = a4[row * 16 + h * 8 + q];
        }
        __syncthreads();
        int kb = h * 32;
        for (int k0 = 0; k0 < 32; k0 += 4) {
            float4 wf0 = *(const float4*)&wt[(kb + k0)     * 64 + c0];
            float4 wf1 = *(const float4*)&wt[(kb + k0 + 1) * 64 + c0];
            float4 wf2 = *(const float4*)&wt[(kb + k0 + 2) * 64 + c0];
            float4 wf3 = *(const float4*)&wt[(kb + k0 + 3) * 64 + c0];
#pragma unroll
            for (int i = 0; i < 8; ++i) {
                float4 af = *(const float4*)&at[(my + i * 16) * AT2_S + k0];
                acc[i][0] = fmaf(af.x, wf0.x, acc[i][0]);   // ascending k: bitwise
                acc[i][0] = fmaf(af.y, wf1.x, acc[i][0]);   // same chain as v3
                acc[i][0] = fmaf(af.z, wf2.x, acc[i][0]);
                acc[i][0] = fmaf(af.w, wf3.x, acc[i][0]);
                acc[i][1] = fmaf(af.x, wf0.y, acc[i][1]);
                acc[i][1] = fmaf(af.y, wf1.y, acc[i][1]);
                acc[i][1] = fmaf(af.z, wf2.y, acc[i][1]);
                acc[i][1] = fmaf(af.w, wf3.y, acc[i][1]);
                acc[i][2] = fmaf(af.x, wf0.z, acc[i][2]);
                acc[i][2] = fmaf(af.y, wf1.z, acc[i][2]);
                acc[i][2] = fmaf(af.z, wf2.z, acc[i][2]);
                acc[i][2] = fmaf(af.w, wf3.z, acc[i][2]);
                acc[i][3] = fmaf(af.x, wf0.w, acc[i][3]);
                acc[i][3] = fmaf(af.y, wf1.w, acc[i][3]);
                acc[i][3] = fmaf(af.z, wf2.w, acc[i][3]);
                acc[i][3] = fmaf(af.w, wf3.w, acc[i][3]);
            }
        }
    }

    // epilogue: bias+relu, run-length over the thread's 8 stride-16 nodes
    // (batch sorted -> gidx still monotone), LDS graph slots, few global atomics
    int nbase = bx * 128;
    int gbase = batch[nbase];                          // block-uniform
    int gidx[8];
#pragma unroll
    for (int i = 0; i < 8; ++i) {
        int node = nbase + my + i * 16;
        gidx[i] = (node < NN) ? batch[node] : -1;
    }
    float bias[4];
#pragma unroll
    for (int j = 0; j < 4; ++j) bias[j] = b2[chb + c0 + j];

#pragma unroll
    for (int j = 0; j < 4; ++j) {
        int run_g = -1;
        float rs = 0.f;
#pragma unroll
        for (int i = 0; i < 8; ++i) {
            if (gidx[i] < 0) break;
            float hcur = fmaxf(acc[i][j] + bias[j], 0.f);
            if (gidx[i] != run_g) {
                if (run_g >= 0) {
                    int slot = run_g - gbase;
                    if (slot < 4) atomicAdd(&lpool[slot * 64 + c0 + j], rs);
                    else          atomicAdd(&pooled[(run_g << 7) + chb + c0 + j], rs);
                }
                run_g = gidx[i]; rs = hcur;
            } else {
                rs += hcur;
            }
        }
        if (run_g >= 0) {
            int slot = run_g - gbase;
            if (slot < 4) atomicAdd(&lpool[slot * 64 + c0 + j], rs);
            else          atomicAdd(&pooled[(run_g << 7) + chb + c0 + j], rs);
        }
    }
    __syncthreads();
    for (int i = tid; i < 4 * 64; i += 256) {
        int slot = i >> 6, c = i & 63;
        int g = gbase + slot;
        float v = lpool[i];
        if (g < NG && v != 0.f) atomicAdd(&pooled[(g << 7) + chb + c], v);
    }
}

// ---------------- FC: out = (pooled/cnt) @ Wfc + bfc ----------------
__device__ __forceinline__ int lower_bound(const int* __restrict__ a, int n, int key) {
    int lo = 0, hi = n;
    while (lo < hi) { int mid = (lo + hi) >> 1; if (a[mid] < key) lo = mid + 1; else hi = mid; }
    return lo;
}

__global__ void k_fc(const float* __restrict__ pooled, const int* __restrict__ batch,
                     const float* __restrict__ Wfc, const float* __restrict__ bfc,
                     float* __restrict__ out) {
    int t = blockIdx.x * blockDim.x + threadIdx.x;
    if (t >= NG * C_OUT) return;
    int g = t >> 1, o = t & 1;
    int start = lower_bound(batch, NN, g);
    int end   = lower_bound(batch, NN, g + 1);
    float inv = 1.f / fmaxf((float)(end - start), 1.f);
    float s = bfc[o];
    for (int cc = 0; cc < C_H2; ++cc)
        s = fmaf(pooled[(g << 7) + cc] * inv, Wfc[cc * C_OUT + o], s);
    out[t] = s;
}

extern "C" void kernel_launch(void* const* d_in, const int* in_sizes, int n_in,
                              void* d_out, int out_size, void* d_ws, size_t ws_size,
                              hipStream_t stream) {
    const float* x     = (const float*)d_in[0];
    const int*   ei    = (const int*)d_in[1];   // [2, E]: row0 = src, row1 = dst
    const int*   batch = (const int*)d_in[2];
    const float* W1    = (const float*)d_in[3];
    const float* b1    = (const float*)d_in[4];
    const float* W2    = (const float*)d_in[5];
    const float* b2    = (const float*)d_in[6];
    const float* Wfc   = (const float*)d_in[7];
    const float* bfc   = (const float*)d_in[8];
    float* out = (float*)d_out;

    // workspace carve-out (~52 MB)
    char* p = (char*)d_ws;
    auto alloc = [&](size_t bytes) { char* r = p; p += (bytes + 255) & ~size_t(255); return r; };
    float*  dinv    = (float*) alloc((size_t)NN * 4);
    int*    row_ptr = (int*)   alloc((size_t)(NN + 1) * 4);
    int*    btot    = (int*)   alloc((size_t)NB * 4);
    int*    bbase   = (int*)   alloc((size_t)(NB + 1) * 4);
    int*    hist    = (int*)   alloc((size_t)NB * PCHUNKS * 4);
    int*    offs    = (int*)   alloc((size_t)NB * PCHUNKS * 4);
    int2*   ed2     = (int2*)  alloc((size_t)NE * 8);
    int*    ed      = (int*)   alloc((size_t)NE * 4);
    float4* x4      = (float4*)alloc((size_t)NN * 16);
    float4* aggx4   = (float4*)alloc((size_t)NN * 16);
    float*  agg1    = (float*) alloc((size_t)(NN + 128) * C_H1 * 4);  // padded
    float*  pooled  = (float*) alloc((size_t)NG * C_H2 * 4);

    hipMemsetAsync(pooled, 0, (size_t)NG * C_H2 * 4, stream);
    k_hist    <<<PCHUNKS, 256, 0, stream>>>(ei, hist);
    k_colscan0<<<NB, 256, 0, stream>>>(hist, offs, btot);
    k_bbase   <<<1, 256, 0, stream>>>(btot, bbase, row_ptr);
    k_scatterA<<<PCHUNKS, 256, 0, stream>>>(ei, offs, bbase, ed2);
    k_B1      <<<NB, 256, 0, stream>>>(ed2, bbase, dinv, row_ptr);
    k_x4      <<<(NN + 255) / 256, 256, 0, stream>>>(x, x4);
    k_scatterB<<<NB, 256, 0, stream>>>(row_ptr, ed2, dinv, x4, ed, aggx4);
    k_edge1   <<<(NN * C_H1) / 256, 256, 0, stream>>>(row_ptr, ed, aggx4, W1, b1, agg1);
    k_mm2pool <<<MM2_BLOCKS * 2, 256, 0, stream>>>(agg1, W2, b2, batch, pooled);
    k_fc      <<<(NG * C_OUT + 255) / 256, 256, 0, stream>>>(pooled, batch, Wfc, bfc, out);
}